// Round 1
// baseline (1785.541 us; speedup 1.0000x reference)
//
#include <hip/hip_runtime.h>
#include <math.h>

#define LL  3
#define EE  1000000
#define NNODE 100000
#define DD  64
#define AAT 8
#define NR2C 461
#define QQ  1000
#define ENTC 10000
#define QE  (QQ * ENTC)

__device__ __forceinline__ float bcast(float v, int l) {
    return __int_as_float(__builtin_amdgcn_readlane(__float_as_int(v), l));
}
__device__ __forceinline__ float sigmoidf_(float x) {
    return 1.0f / (1.0f + __expf(-x));
}
__device__ __forceinline__ float tanhf_(float x) {
    return 1.0f - 2.0f / (__expf(2.0f * x) + 1.0f);
}

__global__ void fill_f32(float* __restrict__ p, int n, float v) {
    int i = blockIdx.x * blockDim.x + threadIdx.x;
    int stride = gridDim.x * blockDim.x;
    float4* p4 = (float4*)p;
    int n4 = n >> 2;
    float4 v4 = make_float4(v, v, v, v);
    for (int j = i; j < n4; j += stride) p4[j] = v4;
}

__global__ void fill_i32(int* __restrict__ p, int n, int v) {
    int i = blockIdx.x * blockDim.x + threadIdx.x;
    int stride = gridDim.x * blockDim.x;
    int4* p4 = (int4*)p;
    int n4 = n >> 2;
    int4 v4 = make_int4(v, v, v, v);
    for (int j = i; j < n4; j += stride) p4[j] = v4;
}

// One wave per edge; lane = d (0..63).
__global__ __launch_bounds__(256) void edge_kernel(
    const int* __restrict__ relation,
    const int* __restrict__ r_idx,
    const int* __restrict__ rel,
    const int* __restrict__ sub,
    const int* __restrict__ obj,
    const float* __restrict__ emb,    // [NR2C*DD] this layer
    const float* __restrict__ Ws,     // [AAT*DD]
    const float* __restrict__ Wr,
    const float* __restrict__ Wqr,
    const float* __restrict__ Wqrb,   // [AAT]
    const float* __restrict__ walw,   // [AAT]
    const float* __restrict__ walb,   // [1]
    const float* __restrict__ h,      // [NNODE*DD]
    float* __restrict__ agg)          // [NNODE*DD]
{
    const int lane = threadIdx.x & 63;
    const int wid = (blockIdx.x * blockDim.x + threadIdx.x) >> 6;
    const int nw = (gridDim.x * blockDim.x) >> 6;

    float ws8[8], wr8[8], wq8[8];
#pragma unroll
    for (int a = 0; a < 8; ++a) {
        ws8[a] = Ws[a * 64 + lane];
        wr8[a] = Wr[a * 64 + lane];
        wq8[a] = Wqr[a * 64 + lane];
    }
    const int aid = lane & 7;
    const float wa = walw[aid];
    const float bq = Wqrb[aid];
    const float wb = walb[0];

    for (int e = wid; e < EE; e += nw) {
        const int eu = __builtin_amdgcn_readfirstlane(e);
        const int s = sub[eu];
        const int r = rel[eu];
        const int q = relation[r_idx[eu]];
        const int o = obj[eu];

        const float hs = h[s * 64 + lane];
        const float hr = emb[r * 64 + lane];
        const float hq = emb[q * 64 + lane];

        float p[8];
#pragma unroll
        for (int a = 0; a < 8; ++a)
            p[a] = hs * ws8[a] + hr * wr8[a] + hq * wq8[a];

        // stage 1: reduce within 8-lane groups (each lane ends with group sums of all 8)
#pragma unroll
        for (int st = 1; st < 8; st <<= 1) {
#pragma unroll
            for (int a = 0; a < 8; ++a)
                p[a] += __shfl_xor(p[a], st, 64);
        }
        // select a = lane&7, then reduce across the 8 groups
        float v = p[0];
#pragma unroll
        for (int j = 1; j < 8; ++j)
            v = (aid == j) ? p[j] : v;
        v += __shfl_xor(v, 8, 64);
        v += __shfl_xor(v, 16, 64);
        v += __shfl_xor(v, 32, 64);

        v = fmaxf(v + bq, 0.0f);           // attn[a], a = lane&7, replicated over groups
        float t = v * wa;
        t += __shfl_xor(t, 1, 64);
        t += __shfl_xor(t, 2, 64);
        t += __shfl_xor(t, 4, 64);
        const float alpha = sigmoidf_(t + wb);

        atomicAdd(&agg[o * 64 + lane], alpha * (hs + hr));
    }
}

// Wave per 4 nodes; lane = output dim. Weights transposed in LDS (112 KB).
__global__ __launch_bounds__(1024, 4) void node_kernel(
    const float* __restrict__ Wh,     // [DD*DD] this layer
    const float* __restrict__ Wih,    // [192*64]
    const float* __restrict__ Whh,    // [192*64]
    const float* __restrict__ bih,    // [192]
    const float* __restrict__ bhh,    // [192]
    float* __restrict__ h,            // [NNODE*DD] in/out
    float* __restrict__ agg)          // [NNODE*DD] read + zeroed
{
    extern __shared__ float lds[];
    float* WhT  = lds;                  // [k*64 + d]
    float* WihT = lds + 4096;           // [k*192 + j]
    float* WhhT = lds + 4096 + 12288;   // [k*192 + j]

    const int t = threadIdx.x;
    for (int m = t; m < 4096; m += 1024)
        WhT[m] = Wh[(m & 63) * 64 + (m >> 6)];
    for (int m = t; m < 12288; m += 1024) {
        int k = m / 192, j = m - k * 192;
        WihT[m] = Wih[j * 64 + k];
        WhhT[m] = Whh[j * 64 + k];
    }
    __syncthreads();

    const int lane = t & 63;
    const int wid = blockIdx.x * 16 + (t >> 6);
    const int nw = gridDim.x * 16;

    const float b_ir = bih[lane], b_iz = bih[64 + lane], b_in = bih[128 + lane];
    const float b_hr = bhh[lane], b_hz = bhh[64 + lane], b_hn = bhh[128 + lane];

    for (int base = wid * 4; base < NNODE; base += nw * 4) {
        float g[4], hv[4];
#pragma unroll
        for (int j = 0; j < 4; ++j) g[j] = agg[(base + j) * 64 + lane];
#pragma unroll
        for (int j = 0; j < 4; ++j) agg[(base + j) * 64 + lane] = 0.0f;
#pragma unroll
        for (int j = 0; j < 4; ++j) hv[j] = h[(base + j) * 64 + lane];

        float x[4] = {0.f, 0.f, 0.f, 0.f};
#pragma unroll 8
        for (int k = 0; k < 64; ++k) {
            float w = WhT[k * 64 + lane];
#pragma unroll
            for (int j = 0; j < 4; ++j)
                x[j] += bcast(g[j], k) * w;
        }
#pragma unroll
        for (int j = 0; j < 4; ++j) x[j] = fmaxf(x[j], 0.0f);

        float ir[4], iz[4], inn[4], hr[4], hz[4], hn[4];
#pragma unroll
        for (int j = 0; j < 4; ++j) {
            ir[j] = b_ir; iz[j] = b_iz; inn[j] = b_in;
            hr[j] = b_hr; hz[j] = b_hz; hn[j] = b_hn;
        }
#pragma unroll 4
        for (int k = 0; k < 64; ++k) {
            const int kb = k * 192;
            float wi0 = WihT[kb + lane];
            float wi1 = WihT[kb + 64 + lane];
            float wi2 = WihT[kb + 128 + lane];
            float wh0 = WhhT[kb + lane];
            float wh1 = WhhT[kb + 64 + lane];
            float wh2 = WhhT[kb + 128 + lane];
#pragma unroll
            for (int j = 0; j < 4; ++j) {
                float xk = bcast(x[j], k);
                float hk = bcast(hv[j], k);
                ir[j] += xk * wi0; iz[j] += xk * wi1; inn[j] += xk * wi2;
                hr[j] += hk * wh0; hz[j] += hk * wh1; hn[j] += hk * wh2;
            }
        }
#pragma unroll
        for (int j = 0; j < 4; ++j) {
            float r = sigmoidf_(ir[j] + hr[j]);
            float z = sigmoidf_(iz[j] + hz[j]);
            float nn = tanhf_(inn[j] + r * hn[j]);
            h[(base + j) * 64 + lane] = (1.0f - z) * nn + z * hv[j];
        }
    }
}

__global__ __launch_bounds__(256) void score_kernel(
    const float* __restrict__ h, const float* __restrict__ Wf,
    float* __restrict__ scores)
{
    const int lane = threadIdx.x & 63;
    const int wid = (blockIdx.x * blockDim.x + threadIdx.x) >> 6;
    const int nw = (gridDim.x * blockDim.x) >> 6;
    const float wf = Wf[lane];
    for (int n = wid; n < NNODE; n += nw) {
        float v = h[n * 64 + lane] * wf;
        v += __shfl_xor(v, 1, 64);
        v += __shfl_xor(v, 2, 64);
        v += __shfl_xor(v, 4, 64);
        v += __shfl_xor(v, 8, 64);
        v += __shfl_xor(v, 16, 64);
        v += __shfl_xor(v, 32, 64);
        if (lane == 0) scores[n] = v;
    }
}

__global__ void scatter_max_kernel(const int* __restrict__ nq, const int* __restrict__ ne,
                                   int* __restrict__ winner)
{
    int n = blockIdx.x * blockDim.x + threadIdx.x;
    if (n < NNODE) {
        int pos = nq[n] * ENTC + ne[n];
        atomicMax(&winner[pos], n);
    }
}

__global__ void scatter_write_kernel(const int* __restrict__ nq, const int* __restrict__ ne,
                                     const int* __restrict__ winner,
                                     const float* __restrict__ scores,
                                     float* __restrict__ out)
{
    int n = blockIdx.x * blockDim.x + threadIdx.x;
    if (n < NNODE) {
        int pos = nq[n] * ENTC + ne[n];
        if (winner[pos] == n) out[pos] = scores[n];
    }
}

extern "C" void kernel_launch(void* const* d_in, const int* in_sizes, int n_in,
                              void* d_out, int out_size, void* d_ws, size_t ws_size,
                              hipStream_t stream)
{
    const int* relation  = (const int*)d_in[0];
    const int* r_idx     = (const int*)d_in[1];
    const int* rel       = (const int*)d_in[2];
    const int* sub       = (const int*)d_in[3];
    const int* obj       = (const int*)d_in[4];
    // d_in[5] = idx (identity permutation; index_copy is a no-op) — unused
    const int* nodes_q   = (const int*)d_in[6];
    const int* nodes_ent = (const int*)d_in[7];
    const float* rela    = (const float*)d_in[8];
    const float* Ws      = (const float*)d_in[9];
    const float* Wr      = (const float*)d_in[10];
    const float* Wqr     = (const float*)d_in[11];
    const float* Wqrb    = (const float*)d_in[12];
    const float* walw    = (const float*)d_in[13];
    const float* walb    = (const float*)d_in[14];
    const float* Wh      = (const float*)d_in[15];
    const float* gWih    = (const float*)d_in[16];
    const float* gWhh    = (const float*)d_in[17];
    const float* gbih    = (const float*)d_in[18];
    const float* gbhh    = (const float*)d_in[19];
    const float* Wf      = (const float*)d_in[20];

    float* ws     = (float*)d_ws;
    float* scores = ws;                      // NNODE floats (padded to 102400)
    float* h      = ws + 102400;             // NNODE*DD
    float* agg    = h + NNODE * DD;          // NNODE*DD
    int*   winner = (int*)(ws + 102400);     // QE ints; overlays h/agg AFTER scores done
    float* out    = (float*)d_out;

    // zero output & state (+agg)
    fill_f32<<<2048, 256, 0, stream>>>(out, QE, 0.0f);
    fill_f32<<<2048, 256, 0, stream>>>(h, 2 * NNODE * DD, 0.0f);

    for (int i = 0; i < LL; ++i) {
        edge_kernel<<<2048, 256, 0, stream>>>(
            relation, r_idx + i * EE, rel + i * EE, sub + i * EE, obj + i * EE,
            rela + i * NR2C * DD,
            Ws + i * AAT * DD, Wr + i * AAT * DD, Wqr + i * AAT * DD,
            Wqrb + i * AAT, walw + i * AAT, walb + i,
            h, agg);
        node_kernel<<<256, 1024, 114688, stream>>>(
            Wh + i * DD * DD, gWih, gWhh, gbih, gbhh, h, agg);
    }

    score_kernel<<<1024, 256, 0, stream>>>(h, Wf, scores);
    // h is dead now; winner overlays its region
    fill_i32<<<2048, 256, 0, stream>>>(winner, QE, -1);
    scatter_max_kernel<<<(NNODE + 255) / 256, 256, 0, stream>>>(nodes_q, nodes_ent, winner);
    scatter_write_kernel<<<(NNODE + 255) / 256, 256, 0, stream>>>(nodes_q, nodes_ent, winner, scores, out);
}

// Round 2
// 1555.070 us; speedup vs baseline: 1.1482x; 1.1482x over previous
//
#include <hip/hip_runtime.h>
#include <math.h>

#define LL  3
#define EE  1000000
#define NNODE 100000
#define DD  64
#define AAT 8
#define NR2C 461
#define QQ  1000
#define ENTC 10000
#define QE  (QQ * ENTC)

__device__ __forceinline__ float bcast(float v, int l) {
    return __int_as_float(__builtin_amdgcn_readlane(__float_as_int(v), l));
}
__device__ __forceinline__ float sigmoidf_(float x) {
    return 1.0f / (1.0f + __expf(-x));
}
__device__ __forceinline__ float tanhf_(float x) {
    return 1.0f - 2.0f / (__expf(2.0f * x) + 1.0f);
}

// Butterfly: input p[a] = lane's partial for output a. Returns full dot for
// a = lane&7 (replicated across the eight 8-lane groups); lanes 0..7 hold a=0..7.
__device__ __forceinline__ float dot8_reduce(float* p, int lane) {
#pragma unroll
    for (int st = 1; st < 8; st <<= 1)
#pragma unroll
        for (int a = 0; a < 8; ++a)
            p[a] += __shfl_xor(p[a], st, 64);
    const int aid = lane & 7;
    float v = p[0];
#pragma unroll
    for (int j = 1; j < 8; ++j)
        v = (aid == j) ? p[j] : v;
    v += __shfl_xor(v, 8, 64);
    v += __shfl_xor(v, 16, 64);
    v += __shfl_xor(v, 32, 64);
    return v;
}

__global__ void fill_f32(float* __restrict__ p, int n, float v) {
    int i = blockIdx.x * blockDim.x + threadIdx.x;
    int stride = gridDim.x * blockDim.x;
    float4* p4 = (float4*)p;
    int n4 = n >> 2;
    float4 v4 = make_float4(v, v, v, v);
    for (int j = i; j < n4; j += stride) p4[j] = v4;
}

__global__ void fill_i32(int* __restrict__ p, int n, int v) {
    int i = blockIdx.x * blockDim.x + threadIdx.x;
    int stride = gridDim.x * blockDim.x;
    int4* p4 = (int4*)p;
    int n4 = n >> 2;
    int4 v4 = make_int4(v, v, v, v);
    for (int j = i; j < n4; j += stride) p4[j] = v4;
}

// s_att[n][a] = sum_k h[n][k] * Ws[a][k]   (one wave per node)
__global__ __launch_bounds__(256) void satt_kernel(
    const float* __restrict__ h, const float* __restrict__ Ws,
    float* __restrict__ s_att)
{
    const int lane = threadIdx.x & 63;
    const int wid = (blockIdx.x * blockDim.x + threadIdx.x) >> 6;
    const int nw = (gridDim.x * blockDim.x) >> 6;
    float w8[8];
#pragma unroll
    for (int a = 0; a < 8; ++a) w8[a] = Ws[a * 64 + lane];
    for (int n = wid; n < NNODE; n += nw) {
        const float hv = h[n * 64 + lane];
        float p[8];
#pragma unroll
        for (int a = 0; a < 8; ++a) p[a] = hv * w8[a];
        float v = dot8_reduce(p, lane);
        if (lane < 8) s_att[n * 8 + lane] = v;
    }
}

// r_att[r][a] = emb[r]@Wr^T  (r<461);  qr_att[j][a] = emb[relation[j]]@Wqr^T + b[a]
__global__ __launch_bounds__(256) void rqatt_kernel(
    const int* __restrict__ relation, const float* __restrict__ emb,
    const float* __restrict__ Wr, const float* __restrict__ Wqr,
    const float* __restrict__ Wqrb,
    float* __restrict__ r_att, float* __restrict__ qr_att)
{
    const int lane = threadIdx.x & 63;
    const int wid = (blockIdx.x * blockDim.x + threadIdx.x) >> 6;
    const int nw = (gridDim.x * blockDim.x) >> 6;
    float wr8[8], wq8[8];
#pragma unroll
    for (int a = 0; a < 8; ++a) {
        wr8[a] = Wr[a * 64 + lane];
        wq8[a] = Wqr[a * 64 + lane];
    }
    for (int i = wid; i < NR2C + QQ; i += nw) {
        const bool isQ = i >= NR2C;
        const int row = isQ ? relation[i - NR2C] : i;
        const float ev = emb[row * 64 + lane];
        float p[8];
#pragma unroll
        for (int a = 0; a < 8; ++a) p[a] = ev * (isQ ? wq8[a] : wr8[a]);
        float v = dot8_reduce(p, lane);
        if (lane < 8) {
            if (isQ) qr_att[(i - NR2C) * 8 + lane] = v + Wqrb[lane];
            else     r_att[i * 8 + lane] = v;
        }
    }
}

// alpha[e] = sigmoid( walpha . relu(s_att[sub]+r_att[rel]+qr_att[r_idx]) + wb )
__global__ __launch_bounds__(256) void alpha_kernel(
    const int* __restrict__ sub, const int* __restrict__ rel,
    const int* __restrict__ r_idx,
    const float* __restrict__ s_att, const float* __restrict__ r_att,
    const float* __restrict__ qr_att,
    const float* __restrict__ walw, const float* __restrict__ walb,
    float* __restrict__ alpha)
{
    const int e = blockIdx.x * blockDim.x + threadIdx.x;
    if (e >= EE) return;
    const float4* sa = (const float4*)(s_att + sub[e] * 8);
    const float4* ra = (const float4*)(r_att + rel[e] * 8);
    const float4* qa = (const float4*)(qr_att + r_idx[e] * 8);
    const float4 s0 = sa[0], s1 = sa[1];
    const float4 r0 = ra[0], r1 = ra[1];
    const float4 q0 = qa[0], q1 = qa[1];
    float t = walb[0];
    t += walw[0] * fmaxf(s0.x + r0.x + q0.x, 0.0f);
    t += walw[1] * fmaxf(s0.y + r0.y + q0.y, 0.0f);
    t += walw[2] * fmaxf(s0.z + r0.z + q0.z, 0.0f);
    t += walw[3] * fmaxf(s0.w + r0.w + q0.w, 0.0f);
    t += walw[4] * fmaxf(s1.x + r1.x + q1.x, 0.0f);
    t += walw[5] * fmaxf(s1.y + r1.y + q1.y, 0.0f);
    t += walw[6] * fmaxf(s1.z + r1.z + q1.z, 0.0f);
    t += walw[7] * fmaxf(s1.w + r1.w + q1.w, 0.0f);
    alpha[e] = sigmoidf_(t);
}

// agg[obj] += alpha * (h[sub] + emb[rel])   (one wave per edge, lane = d)
__global__ __launch_bounds__(256) void message_kernel(
    const int* __restrict__ sub, const int* __restrict__ rel,
    const int* __restrict__ obj, const float* __restrict__ alpha,
    const float* __restrict__ h, const float* __restrict__ emb,
    float* __restrict__ agg)
{
    const int lane = threadIdx.x & 63;
    const int wid = (blockIdx.x * blockDim.x + threadIdx.x) >> 6;
    const int nw = (gridDim.x * blockDim.x) >> 6;
    for (int e = wid; e < EE; e += nw) {
        const int eu = __builtin_amdgcn_readfirstlane(e);
        const int s = sub[eu];
        const int r = rel[eu];
        const int o = obj[eu];
        const float a = alpha[eu];
        atomicAdd(&agg[o * 64 + lane], a * (h[s * 64 + lane] + emb[r * 64 + lane]));
    }
}

// Wave per 4 nodes; lane = output dim. Weights transposed in LDS (112 KB).
__global__ __launch_bounds__(1024, 4) void node_kernel(
    const float* __restrict__ Wh,
    const float* __restrict__ Wih,
    const float* __restrict__ Whh,
    const float* __restrict__ bih,
    const float* __restrict__ bhh,
    float* __restrict__ h,
    float* __restrict__ agg)
{
    extern __shared__ float lds[];
    float* WhT  = lds;
    float* WihT = lds + 4096;
    float* WhhT = lds + 4096 + 12288;

    const int t = threadIdx.x;
    for (int m = t; m < 4096; m += 1024)
        WhT[m] = Wh[(m & 63) * 64 + (m >> 6)];
    for (int m = t; m < 12288; m += 1024) {
        int k = m / 192, j = m - k * 192;
        WihT[m] = Wih[j * 64 + k];
        WhhT[m] = Whh[j * 64 + k];
    }
    __syncthreads();

    const int lane = t & 63;
    const int wid = blockIdx.x * 16 + (t >> 6);
    const int nw = gridDim.x * 16;

    const float b_ir = bih[lane], b_iz = bih[64 + lane], b_in = bih[128 + lane];
    const float b_hr = bhh[lane], b_hz = bhh[64 + lane], b_hn = bhh[128 + lane];

    for (int base = wid * 4; base < NNODE; base += nw * 4) {
        float g[4], hv[4];
#pragma unroll
        for (int j = 0; j < 4; ++j) g[j] = agg[(base + j) * 64 + lane];
#pragma unroll
        for (int j = 0; j < 4; ++j) agg[(base + j) * 64 + lane] = 0.0f;
#pragma unroll
        for (int j = 0; j < 4; ++j) hv[j] = h[(base + j) * 64 + lane];

        float x[4] = {0.f, 0.f, 0.f, 0.f};
#pragma unroll 8
        for (int k = 0; k < 64; ++k) {
            float w = WhT[k * 64 + lane];
#pragma unroll
            for (int j = 0; j < 4; ++j)
                x[j] += bcast(g[j], k) * w;
        }
#pragma unroll
        for (int j = 0; j < 4; ++j) x[j] = fmaxf(x[j], 0.0f);

        float ir[4], iz[4], inn[4], hr[4], hz[4], hn[4];
#pragma unroll
        for (int j = 0; j < 4; ++j) {
            ir[j] = b_ir; iz[j] = b_iz; inn[j] = b_in;
            hr[j] = b_hr; hz[j] = b_hz; hn[j] = b_hn;
        }
#pragma unroll 4
        for (int k = 0; k < 64; ++k) {
            const int kb = k * 192;
            float wi0 = WihT[kb + lane];
            float wi1 = WihT[kb + 64 + lane];
            float wi2 = WihT[kb + 128 + lane];
            float wh0 = WhhT[kb + lane];
            float wh1 = WhhT[kb + 64 + lane];
            float wh2 = WhhT[kb + 128 + lane];
#pragma unroll
            for (int j = 0; j < 4; ++j) {
                float xk = bcast(x[j], k);
                float hk = bcast(hv[j], k);
                ir[j] += xk * wi0; iz[j] += xk * wi1; inn[j] += xk * wi2;
                hr[j] += hk * wh0; hz[j] += hk * wh1; hn[j] += hk * wh2;
            }
        }
#pragma unroll
        for (int j = 0; j < 4; ++j) {
            float r = sigmoidf_(ir[j] + hr[j]);
            float z = sigmoidf_(iz[j] + hz[j]);
            float nn = tanhf_(inn[j] + r * hn[j]);
            h[(base + j) * 64 + lane] = (1.0f - z) * nn + z * hv[j];
        }
    }
}

__global__ __launch_bounds__(256) void score_kernel(
    const float* __restrict__ h, const float* __restrict__ Wf,
    float* __restrict__ scores)
{
    const int lane = threadIdx.x & 63;
    const int wid = (blockIdx.x * blockDim.x + threadIdx.x) >> 6;
    const int nw = (gridDim.x * blockDim.x) >> 6;
    const float wf = Wf[lane];
    for (int n = wid; n < NNODE; n += nw) {
        float v = h[n * 64 + lane] * wf;
        v += __shfl_xor(v, 1, 64);
        v += __shfl_xor(v, 2, 64);
        v += __shfl_xor(v, 4, 64);
        v += __shfl_xor(v, 8, 64);
        v += __shfl_xor(v, 16, 64);
        v += __shfl_xor(v, 32, 64);
        if (lane == 0) scores[n] = v;
    }
}

__global__ void scatter_max_kernel(const int* __restrict__ nq, const int* __restrict__ ne,
                                   int* __restrict__ winner)
{
    int n = blockIdx.x * blockDim.x + threadIdx.x;
    if (n < NNODE) {
        int pos = nq[n] * ENTC + ne[n];
        atomicMax(&winner[pos], n);
    }
}

__global__ void scatter_write_kernel(const int* __restrict__ nq, const int* __restrict__ ne,
                                     const int* __restrict__ winner,
                                     const float* __restrict__ scores,
                                     float* __restrict__ out)
{
    int n = blockIdx.x * blockDim.x + threadIdx.x;
    if (n < NNODE) {
        int pos = nq[n] * ENTC + ne[n];
        if (winner[pos] == n) out[pos] = scores[n];
    }
}

extern "C" void kernel_launch(void* const* d_in, const int* in_sizes, int n_in,
                              void* d_out, int out_size, void* d_ws, size_t ws_size,
                              hipStream_t stream)
{
    const int* relation  = (const int*)d_in[0];
    const int* r_idx     = (const int*)d_in[1];
    const int* rel       = (const int*)d_in[2];
    const int* sub       = (const int*)d_in[3];
    const int* obj       = (const int*)d_in[4];
    // d_in[5] = idx (identity permutation; index_copy is a no-op) — unused
    const int* nodes_q   = (const int*)d_in[6];
    const int* nodes_ent = (const int*)d_in[7];
    const float* rela    = (const float*)d_in[8];
    const float* Ws      = (const float*)d_in[9];
    const float* Wr      = (const float*)d_in[10];
    const float* Wqr     = (const float*)d_in[11];
    const float* Wqrb    = (const float*)d_in[12];
    const float* walw    = (const float*)d_in[13];
    const float* walb    = (const float*)d_in[14];
    const float* Wh      = (const float*)d_in[15];
    const float* gWih    = (const float*)d_in[16];
    const float* gWhh    = (const float*)d_in[17];
    const float* gbih    = (const float*)d_in[18];
    const float* gbhh    = (const float*)d_in[19];
    const float* Wf      = (const float*)d_in[20];

    float* ws     = (float*)d_ws;
    float* scores = ws;                      // NNODE floats (padded to 102400)
    float* h      = ws + 102400;             // NNODE*DD
    float* agg    = h + NNODE * DD;          // NNODE*DD
    int*   winner = (int*)(ws + 102400);     // QE ints; overlays h/agg AFTER scores done
    float* out    = (float*)d_out;

    // d_out doubles as scratch during the layers (dead until final scatter;
    // zero-filled just before the winner pass).
    float* alpha  = (float*)d_out;           // EE floats
    float* s_att  = alpha + EE;              // NNODE*8
    float* r_att  = s_att + NNODE * 8;       // 461*8
    float* qr_att = r_att + NR2C * 8;        // 1000*8
    // total scratch in d_out: ~1.81M floats << QE (10M)

    fill_f32<<<2048, 256, 0, stream>>>(h, 2 * NNODE * DD, 0.0f);

    for (int i = 0; i < LL; ++i) {
        const float* emb = rela + i * NR2C * DD;
        satt_kernel<<<512, 256, 0, stream>>>(h, Ws + i * AAT * DD, s_att);
        rqatt_kernel<<<184, 256, 0, stream>>>(relation, emb,
            Wr + i * AAT * DD, Wqr + i * AAT * DD, Wqrb + i * AAT, r_att, qr_att);
        alpha_kernel<<<(EE + 255) / 256, 256, 0, stream>>>(
            sub + i * EE, rel + i * EE, r_idx + i * EE,
            s_att, r_att, qr_att, walw + i * AAT, walb + i, alpha);
        message_kernel<<<4096, 256, 0, stream>>>(
            sub + i * EE, rel + i * EE, obj + i * EE, alpha, h, emb, agg);
        node_kernel<<<256, 1024, 114688, stream>>>(
            Wh + i * DD * DD, gWih, gWhh, gbih, gbhh, h, agg);
    }

    score_kernel<<<1024, 256, 0, stream>>>(h, Wf, scores);
    // h/agg and the d_out scratch are dead now.
    fill_f32<<<2048, 256, 0, stream>>>(out, QE, 0.0f);
    fill_i32<<<2048, 256, 0, stream>>>(winner, QE, -1);
    scatter_max_kernel<<<(NNODE + 255) / 256, 256, 0, stream>>>(nodes_q, nodes_ent, winner);
    scatter_write_kernel<<<(NNODE + 255) / 256, 256, 0, stream>>>(nodes_q, nodes_ent, winner, scores, out);
}